// Round 3
// baseline (230.101 us; speedup 1.0000x reference)
//
#include <hip/hip_runtime.h>
#include <stdint.h>

// Problem constants (fixed by reference)
#define B_  32
#define N_  128
#define NIN 16
#define K_  4
#define E_  (N_*(N_-1))   // 16256

typedef float    f4 __attribute__((ext_vector_type(4)));
typedef _Float16 h8 __attribute__((ext_vector_type(8)));   // 8 fp16 = 4 VGPRs
typedef _Float16 h4 __attribute__((ext_vector_type(4)));   // 4 fp16 = 2 VGPRs

// ---------------------------------------------------------------------------
// Prep (single launch, block ranges):
//   [0,4096):      S/R per-node layer-1 halves (fp16)
//   [4096,4160):   W2 -> fp16 MFMA B-operand fragments
//   [4160,12352):  rel_types -> rtn[k][b][r][s] fp16, diagonal zeroed
//                  (sender-indexed: s = j + (j>=r); inverse j = s - (s>r))
// ---------------------------------------------------------------------------
__global__ __launch_bounds__(256) void prep(
    const float* __restrict__ inp, const float* __restrict__ W1,
    const float* __restrict__ b1,  const float* __restrict__ W2,
    const float* __restrict__ rt,
    _Float16* __restrict__ Sh, _Float16* __restrict__ Rh,
    _Float16* __restrict__ w2h, _Float16* __restrict__ rtn)
{
    const int bid = blockIdx.x;
    const int tid = threadIdx.x;
    if (bid < 4096) {
        // S[k][b][n][c] = x[b][n][:]@W1[k][:16][c];  R = x@W1[k][16:][c] + b1
        int gid = bid*256 + tid;            // c:6 | n:7 | b:5 | k:2
        int c = gid & 63;
        int n = (gid >> 6) & 127;
        int b = (gid >> 13) & 31;
        int k = gid >> 18;
        float s = 0.f, r = 0.f;
        const float* w1s = W1 + (k*32)*64 + c;
        const float* w1r = W1 + (k*32 + 16)*64 + c;
        const float* xp  = inp + (b*NIN)*N_ + n;    // inputs[b][f][n]
        #pragma unroll
        for (int f = 0; f < 16; ++f) {
            float xv = xp[f*N_];
            s += xv * w1s[f*64];
            r += xv * w1r[f*64];
        }
        r += b1[k*64 + c];
        Sh[gid] = (_Float16)s;
        Rh[gid] = (_Float16)r;
    } else if (bid < 4160) {
        // B-fragment: lane holds B[kk=q*8+i][n=lane&15]; idx (k,ks,nt,lane,i)
        int t = (bid - 4096)*256 + tid;     // i:3 | lane:6 | nt:2 | ks:1 | k:2
        int i    = t & 7;
        int lane = (t >> 3) & 63;
        int nt   = (t >> 9) & 3;
        int ks   = (t >> 11) & 1;
        int k    = t >> 12;
        int c = ks*32 + (lane >> 4)*8 + i;
        int o = nt*16 + (lane & 15);
        w2h[t] = (_Float16)W2[(k*64 + c)*64 + o];
    } else {
        // rtn[k][b][r][s]: sender-indexed edge weight, 0 on diagonal
        int t = (bid - 4160)*256 + tid;     // s:7 | r:7 | b:5 | k:2
        int s = t & 127;
        int r = (t >> 7) & 127;
        int b = (t >> 14) & 31;
        int k = t >> 19;
        _Float16 v = (_Float16)0.f;
        if (s != r) {
            int j = s - (s > r ? 1 : 0);
            v = (_Float16)rt[(b*E_ + r*127 + j)*4 + k];
        }
        rtn[t] = v;
    }
}

// ---------------------------------------------------------------------------
// Edge MLP (fp16 MFMA) + receiver aggregation.
// Block = (b, group of 4 receivers), 8 waves: wave = (k, half-of-M).
// S-fragments (A operand, sender-indexed) loaded ONCE, reused for 4 receivers.
// ---------------------------------------------------------------------------
__global__ __launch_bounds__(512, 4) void edge_mfma(
    const _Float16* __restrict__ Sh, const _Float16* __restrict__ Rh,
    const _Float16* __restrict__ w2h, const _Float16* __restrict__ rtn,
    const float* __restrict__ b2, float* __restrict__ agg)
{
    __shared__ float aggW[8][4][64];

    const int tid  = threadIdx.x;
    const int wave = tid >> 6;       // 0..7
    const int k    = wave >> 1;      // edge type
    const int m0   = (wave & 1)*64;  // sender half
    const int lane = tid & 63;
    const int col  = lane & 15;
    const int q    = lane >> 4;
    const int b     = blockIdx.x >> 5;
    const int rbase = (blockIdx.x & 31)*4;
    const int kb    = k*B_ + b;

    const h8* Sv  = (const h8*)Sh;
    const h8* Rv  = (const h8*)Rh;
    const h8* w2v = (const h8*)w2h;

    // A-fragments: sender rows m = m0 + mt*16 + col (shared across receivers)
    h8 sf[4][2];
    #pragma unroll
    for (int mt = 0; mt < 4; ++mt) {
        int row = (kb*N_ + m0 + mt*16 + col)*8;
        sf[mt][0] = Sv[row + q];
        sf[mt][1] = Sv[row + 4 + q];
    }

    // W2 B-operand fragments
    h8 w2f[2][4];
    #pragma unroll
    for (int ks = 0; ks < 2; ++ks)
        #pragma unroll
        for (int nt = 0; nt < 4; ++nt)
            w2f[ks][nt] = w2v[((k*2 + ks)*4 + nt)*64 + lane];

    // b2 folded into accumulator init (C col = lane&15 for all 4 regs)
    f4 b2i[4];
    #pragma unroll
    for (int nt = 0; nt < 4; ++nt) {
        float v = b2[k*64 + nt*16 + col];
        b2i[nt][0] = v; b2i[nt][1] = v; b2i[nt][2] = v; b2i[nt][3] = v;
    }

    const h8 zero8 = {0,0,0,0,0,0,0,0};

    #pragma unroll
    for (int rg = 0; rg < 4; ++rg) {
        const int r    = rbase + rg;
        const int rowR = (kb*N_ + r)*8;
        h8 rf0 = Rv[rowR + q];
        h8 rf1 = Rv[rowR + 4 + q];
        const h4* rtp = (const h4*)(rtn + (kb*N_ + r)*N_ + m0);

        float aggacc[4] = {0.f, 0.f, 0.f, 0.f};
        #pragma unroll
        for (int mt = 0; mt < 4; ++mt) {
            // h1 = relu(S[sender] + R[recv]), packed fp16
            h8 a0 = __builtin_elementwise_max(sf[mt][0] + rf0, zero8);
            h8 a1 = __builtin_elementwise_max(sf[mt][1] + rf1, zero8);
            h4 rth = rtp[mt*4 + q];          // weights for rows q*4..q*4+3
            float rtv[4];
            #pragma unroll
            for (int i = 0; i < 4; ++i) rtv[i] = (float)rth[i];

            #pragma unroll
            for (int nt = 0; nt < 4; ++nt) {
                f4 acc = __builtin_amdgcn_mfma_f32_16x16x32_f16(a0, w2f[0][nt], b2i[nt], 0, 0, 0);
                acc     = __builtin_amdgcn_mfma_f32_16x16x32_f16(a1, w2f[1][nt], acc,    0, 0, 0);
                // C/D: col = lane&15, row = q*4 + reg
                #pragma unroll
                for (int i = 0; i < 4; ++i)
                    aggacc[nt] += rtv[i] * fmaxf(acc[i], 0.f);
            }
        }
        // cross-quad reduce (rows live in quads) -> LDS partial per wave
        #pragma unroll
        for (int nt = 0; nt < 4; ++nt) {
            float v = aggacc[nt];
            v += __shfl_xor(v, 16, 64);
            v += __shfl_xor(v, 32, 64);
            if (lane < 16) aggW[wave][rg][nt*16 + lane] = v;
        }
    }
    __syncthreads();

    // reduce over 8 waves (4 k x 2 halves), write agg[b][r][c]
    if (tid < 256) {
        int rg = tid >> 6, c = tid & 63;
        float s = 0.f;
        #pragma unroll
        for (int w = 0; w < 8; ++w) s += aggW[w][rg][c];
        agg[(b*N_ + rbase + rg)*64 + c] = s;
    }
}

// ---------------------------------------------------------------------------
// Node MLP (fp32): one block (1 wave) per (b, r).
// ---------------------------------------------------------------------------
__global__ __launch_bounds__(64) void node_mlp(
    const float* __restrict__ agg, const float* __restrict__ inp,
    const float* __restrict__ Wo1, const float* __restrict__ bo1,
    const float* __restrict__ Wo2, const float* __restrict__ bo2,
    const float* __restrict__ Wo3, const float* __restrict__ bo3,
    float* __restrict__ out)
{
    __shared__ float aug[80];
    __shared__ float h1[64];
    __shared__ float h2[64];
    const int tid = threadIdx.x;
    const int b = blockIdx.x >> 7;
    const int r = blockIdx.x & 127;

    if (tid < 16) aug[tid] = inp[(b*NIN + tid)*N_ + r];
    aug[16 + tid] = agg[(b*N_ + r)*64 + tid];
    __syncthreads();

    float s = bo1[tid];
    #pragma unroll 8
    for (int i = 0; i < 80; ++i) s += aug[i] * Wo1[i*64 + tid];
    h1[tid] = fmaxf(s, 0.f);
    __syncthreads();

    s = bo2[tid];
    #pragma unroll 8
    for (int i = 0; i < 64; ++i) s += h1[i] * Wo2[i*64 + tid];
    h2[tid] = fmaxf(s, 0.f);
    __syncthreads();

    if (tid < 16) {
        s = bo3[tid];
        #pragma unroll 8
        for (int i = 0; i < 64; ++i) s += h2[i] * Wo3[i*16 + tid];
        out[(b*NIN + tid)*N_ + r] = s;   // pred transposed: [B, n_out, N]
    }
}

// ---------------------------------------------------------------------------
extern "C" void kernel_launch(void* const* d_in, const int* in_sizes, int n_in,
                              void* d_out, int out_size, void* d_ws, size_t ws_size,
                              hipStream_t stream)
{
    const float* inp = (const float*)d_in[0];
    // d_in[1] = rel_rec, d_in[2] = rel_send: one-hot, decoded analytically, unused
    const float* rt  = (const float*)d_in[3];
    const float* W1  = (const float*)d_in[4];
    const float* b1  = (const float*)d_in[5];
    const float* W2  = (const float*)d_in[6];
    const float* b2  = (const float*)d_in[7];
    const float* Wo1 = (const float*)d_in[8];
    const float* bo1 = (const float*)d_in[9];
    const float* Wo2 = (const float*)d_in[10];
    const float* bo2 = (const float*)d_in[11];
    const float* Wo3 = (const float*)d_in[12];
    const float* bo3 = (const float*)d_in[13];

    // ws layout: Sh 2MB | Rh 2MB | w2h 32KB | rtn 4MB (fp16) | agg 2MB  (~10.03MB)
    _Float16* Sh  = (_Float16*)d_ws;
    _Float16* Rh  = Sh + (1u << 20);
    _Float16* w2h = Rh + (1u << 20);
    _Float16* rtn = w2h + 16384;
    float*    agg = (float*)(rtn + (1u << 21));

    hipLaunchKernelGGL(prep, dim3(12352), dim3(256), 0, stream,
                       inp, W1, b1, W2, rt, Sh, Rh, w2h, rtn);
    hipLaunchKernelGGL(edge_mfma, dim3(B_*N_/4), dim3(512), 0, stream,
                       Sh, Rh, w2h, rtn, b2, agg);
    hipLaunchKernelGGL(node_mlp, dim3(B_*N_), dim3(64), 0, stream,
                       agg, inp, Wo1, bo1, Wo2, bo2, Wo3, bo3, (float*)d_out);
}

// Round 4
// 140.469 us; speedup vs baseline: 1.6381x; 1.6381x over previous
//
#include <hip/hip_runtime.h>
#include <stdint.h>

// Problem constants (fixed by reference)
#define B_  32
#define N_  128
#define NIN 16
#define K_  4
#define E_  (N_*(N_-1))   // 16256

typedef float    f4 __attribute__((ext_vector_type(4)));
typedef _Float16 h8 __attribute__((ext_vector_type(8)));   // 8 fp16 = 4 VGPRs
typedef _Float16 h4 __attribute__((ext_vector_type(4)));   // 4 fp16 = 2 VGPRs

// ---------------------------------------------------------------------------
// Prep (single launch, block ranges):
//   [0,4096):        S/R per-node layer-1 halves (fp16)
//   [4096,4160):     W2 -> fp16 MFMA B-operand fragments
//   [4160,4672):     rel_types -> rtn[k][b][r][s] fp16, diagonal zeroed
//                    (sender-indexed: s = j + (j>=r)); coalesced float4 reads
// ---------------------------------------------------------------------------
__global__ __launch_bounds__(256) void prep(
    const float* __restrict__ inp, const float* __restrict__ W1,
    const float* __restrict__ b1,  const float* __restrict__ W2,
    const float* __restrict__ rt,
    _Float16* __restrict__ Sh, _Float16* __restrict__ Rh,
    _Float16* __restrict__ w2h, _Float16* __restrict__ rtn)
{
    const int bid = blockIdx.x;
    const int tid = threadIdx.x;
    if (bid < 4096) {
        // S[k][b][n][c] = x[b][n][:]@W1[k][:16][c];  R = x@W1[k][16:][c] + b1
        int gid = bid*256 + tid;            // c:6 | n:7 | b:5 | k:2
        int c = gid & 63;
        int n = (gid >> 6) & 127;
        int b = (gid >> 13) & 31;
        int k = gid >> 18;
        float s = 0.f, r = 0.f;
        const float* w1s = W1 + (k*32)*64 + c;
        const float* w1r = W1 + (k*32 + 16)*64 + c;
        const float* xp  = inp + (b*NIN)*N_ + n;    // inputs[b][f][n]
        #pragma unroll
        for (int f = 0; f < 16; ++f) {
            float xv = xp[f*N_];
            s += xv * w1s[f*64];
            r += xv * w1r[f*64];
        }
        r += b1[k*64 + c];
        Sh[gid] = (_Float16)s;
        Rh[gid] = (_Float16)r;
    } else if (bid < 4160) {
        // B-fragment for mfma_f32_16x16x32_f16: lane holds B[kk=q*8+i][n=lane&15]
        int t = (bid - 4096)*256 + tid;     // i:3 | lane:6 | nt:2 | ks:1 | k:2
        int i    = t & 7;
        int lane = (t >> 3) & 63;
        int nt   = (t >> 9) & 3;
        int ks   = (t >> 11) & 1;
        int k    = t >> 12;
        int c = ks*32 + (lane >> 4)*8 + i;
        int o = nt*16 + (lane & 15);
        w2h[t] = (_Float16)W2[(k*64 + c)*64 + o];
    } else {
        // rtn[k][b][r][s]: sender-indexed edge weight, 0 on diagonal.
        // thread <-> (b, r, jg); reads float4 over k (fully coalesced).
        int t = (bid - 4160)*256 + tid;     // jg:5 | r:7 | b:5
        int jg = t & 31;
        int r  = (t >> 5) & 127;
        int b  = t >> 12;
        const f4* rt4p = (const f4*)(rt + (size_t)(b*E_ + r*127)*4);
        #pragma unroll
        for (int u = 0; u < 4; ++u) {
            int j = jg*4 + u;
            if (j < 127) {
                f4 v = rt4p[j];
                int s = j + (j >= r ? 1 : 0);
                #pragma unroll
                for (int k = 0; k < 4; ++k)
                    rtn[((k*B_ + b)*N_ + r)*N_ + s] = (_Float16)v[k];
            } else {
                #pragma unroll
                for (int k = 0; k < 4; ++k)      // zero the diagonal
                    rtn[((k*B_ + b)*N_ + r)*N_ + r] = (_Float16)0.f;
            }
        }
    }
}

// ---------------------------------------------------------------------------
// Edge MLP (fp16 MFMA) + receiver aggregation.
// Block = (k, b, quarter-of-receivers): 512 blocks x 512 threads (8 waves).
// S[k][b] (128x64 fp16, 16KB) staged in LDS once, XOR-swizzled in 16B chunks
// so fragment reads (row stride 128B) are conflict-free. Wave = 4 receivers,
// all 128 senders. No cross-wave reduction: aggK[k][b][r][c] written direct.
// Register budget ~105 (w2f 32 + b2i 16 + rth 16 + rf 8 + acc/misc) < 128.
// ---------------------------------------------------------------------------
__global__ __launch_bounds__(512) void edge_mfma(
    const _Float16* __restrict__ Sh, const _Float16* __restrict__ Rh,
    const _Float16* __restrict__ w2h, const _Float16* __restrict__ rtn,
    const float* __restrict__ b2, float* __restrict__ aggK)
{
    __shared__ _Float16 Ssw[N_*64];     // 16 KB, XOR-swizzled 16B chunks

    const int tid  = threadIdx.x;
    const int wave = tid >> 6;
    const int lane = tid & 63;
    const int col  = lane & 15;
    const int q    = lane >> 4;
    const int bid  = blockIdx.x;        // (k*32 + b)*4 + rt4
    const int rt4  = bid & 3;
    const int b    = (bid >> 2) & 31;
    const int k    = bid >> 7;
    const int kb   = k*B_ + b;

    // ---- stage S[k][b] into LDS, chunk p = s*8 + (c8 ^ (s&7)) ----
    const _Float16* Sg = Sh + (size_t)kb*(N_*64);
    #pragma unroll
    for (int rnd = 0; rnd < 2; ++rnd) {
        int p  = rnd*512 + tid;
        int s  = p >> 3;
        int c8 = (p & 7) ^ (s & 7);
        h8 v = *(const h8*)(Sg + (s*8 + c8)*8);
        *(h8*)(Ssw + p*8) = v;
    }

    // W2 B-operand fragments (held; ~2KB per k, L2-broadcast)
    const h8* w2v = (const h8*)w2h;
    h8 w2f[2][4];
    #pragma unroll
    for (int ks = 0; ks < 2; ++ks)
        #pragma unroll
        for (int nt = 0; nt < 4; ++nt)
            w2f[ks][nt] = w2v[((k*2 + ks)*4 + nt)*64 + lane];

    // b2 folded into accumulator init (C col = lane&15 for all 4 regs)
    f4 b2i[4];
    #pragma unroll
    for (int nt = 0; nt < 4; ++nt) {
        float v = b2[k*64 + nt*16 + col];
        b2i[nt][0] = v; b2i[nt][1] = v; b2i[nt][2] = v; b2i[nt][3] = v;
    }

    __syncthreads();

    const h8* Rv = (const h8*)Rh;
    const _Float16* rtbase = rtn + (size_t)kb*(N_*N_);
    const h8 zero8 = {0,0,0,0,0,0,0,0};

    #pragma unroll 1
    for (int rg = 0; rg < 4; ++rg) {
        const int r = rt4*32 + wave*4 + rg;
        // per-receiver prefetch: R row (broadcast) + rtn row slices
        h8 rf0 = Rv[(kb*N_ + r)*8 + q];
        h8 rf1 = Rv[(kb*N_ + r)*8 + 4 + q];
        const h4* rtp = (const h4*)(rtbase + r*N_);
        h4 rth[8];
        #pragma unroll
        for (int mt = 0; mt < 8; ++mt) rth[mt] = rtp[mt*4 + q];

        float aggacc[4] = {0.f, 0.f, 0.f, 0.f};
        #pragma unroll
        for (int mt = 0; mt < 8; ++mt) {
            int s  = mt*16 + col;                   // A row = lane&15
            int x0 = (s*8 + (q       ^ (s & 7)))*8; // chunk c8 = q
            int x1 = (s*8 + ((4 + q) ^ (s & 7)))*8; // chunk c8 = 4+q
            h8 a0 = *(const h8*)(Ssw + x0);
            h8 a1 = *(const h8*)(Ssw + x1);
            a0 = __builtin_elementwise_max(a0 + rf0, zero8);  // h1 = relu(S+R)
            a1 = __builtin_elementwise_max(a1 + rf1, zero8);
            float rtv[4];
            #pragma unroll
            for (int i = 0; i < 4; ++i) rtv[i] = (float)rth[mt][i];

            #pragma unroll
            for (int nt = 0; nt < 4; ++nt) {
                f4 acc = __builtin_amdgcn_mfma_f32_16x16x32_f16(a0, w2f[0][nt], b2i[nt], 0, 0, 0);
                acc     = __builtin_amdgcn_mfma_f32_16x16x32_f16(a1, w2f[1][nt], acc,    0, 0, 0);
                // C/D: col = lane&15, row = q*4 + reg
                #pragma unroll
                for (int i = 0; i < 4; ++i)
                    aggacc[nt] += rtv[i] * fmaxf(acc[i], 0.f);
            }
        }
        // rows live in quads -> cross-quad reduce, 16 lanes store
        #pragma unroll
        for (int nt = 0; nt < 4; ++nt) {
            float v = aggacc[nt];
            v += __shfl_xor(v, 16, 64);
            v += __shfl_xor(v, 32, 64);
            if (lane < 16) aggK[((size_t)kb*N_ + r)*64 + nt*16 + lane] = v;
        }
    }
}

// ---------------------------------------------------------------------------
// Node MLP (fp32): 512 blocks x 256 thr; weights staged in LDS once/block;
// 8 nodes per block (2 per wave), wave-local compute (no inner barriers).
// ---------------------------------------------------------------------------
__global__ __launch_bounds__(256) void node_mlp(
    const float* __restrict__ aggK, const float* __restrict__ inp,
    const float* __restrict__ Wo1, const float* __restrict__ bo1,
    const float* __restrict__ Wo2, const float* __restrict__ bo2,
    const float* __restrict__ Wo3, const float* __restrict__ bo3,
    float* __restrict__ out)
{
    __shared__ float W1s[80*64];      // 20 KB
    __shared__ float W2s[64*64];      // 16 KB
    __shared__ float W3s[64*16];      // 4 KB
    __shared__ float bs[144];         // bo1|bo2|bo3
    __shared__ float augs[4][2][80];
    __shared__ float h1s[4][2][64];
    __shared__ float h2s[4][2][64];

    const int tid  = threadIdx.x;
    const int wave = tid >> 6;
    const int lane = tid & 63;

    for (int i = tid; i < 80*64; i += 256) W1s[i] = Wo1[i];
    for (int i = tid; i < 64*64; i += 256) W2s[i] = Wo2[i];
    for (int i = tid; i < 64*16; i += 256) W3s[i] = Wo3[i];
    if (tid < 64)  bs[tid] = bo1[tid];
    else if (tid < 128) bs[tid] = bo2[tid - 64];
    else if (tid < 144) bs[tid] = bo3[tid - 128];
    __syncthreads();

    #pragma unroll
    for (int t = 0; t < 2; ++t) {
        const int node = blockIdx.x*8 + wave*2 + t;
        const int b = node >> 7, r = node & 127;
        if (lane < 16) augs[wave][t][lane] = inp[(b*NIN + lane)*N_ + r];
        float a = 0.f;
        #pragma unroll
        for (int k = 0; k < 4; ++k)
            a += aggK[(((size_t)k*B_ + b)*N_ + r)*64 + lane];
        augs[wave][t][16 + lane] = a;

        float s = bs[lane];
        #pragma unroll 8
        for (int i = 0; i < 80; ++i) s += augs[wave][t][i] * W1s[i*64 + lane];
        h1s[wave][t][lane] = fmaxf(s, 0.f);

        s = bs[64 + lane];
        #pragma unroll 8
        for (int i = 0; i < 64; ++i) s += h1s[wave][t][i] * W2s[i*64 + lane];
        h2s[wave][t][lane] = fmaxf(s, 0.f);

        if (lane < 16) {
            s = bs[128 + lane];
            #pragma unroll 8
            for (int i = 0; i < 64; ++i) s += h2s[wave][t][i] * W3s[i*16 + lane];
            out[(b*NIN + lane)*N_ + r] = s;   // pred transposed: [B, n_out, N]
        }
    }
}

// ---------------------------------------------------------------------------
extern "C" void kernel_launch(void* const* d_in, const int* in_sizes, int n_in,
                              void* d_out, int out_size, void* d_ws, size_t ws_size,
                              hipStream_t stream)
{
    const float* inp = (const float*)d_in[0];
    // d_in[1] = rel_rec, d_in[2] = rel_send: one-hot, decoded analytically, unused
    const float* rt  = (const float*)d_in[3];
    const float* W1  = (const float*)d_in[4];
    const float* b1  = (const float*)d_in[5];
    const float* W2  = (const float*)d_in[6];
    const float* b2  = (const float*)d_in[7];
    const float* Wo1 = (const float*)d_in[8];
    const float* bo1 = (const float*)d_in[9];
    const float* Wo2 = (const float*)d_in[10];
    const float* bo2 = (const float*)d_in[11];
    const float* Wo3 = (const float*)d_in[12];
    const float* bo3 = (const float*)d_in[13];

    // ws: Sh 2MB | Rh 2MB | w2h 32KB | rtn 4MB fp16 | aggK 4MB fp32 (~12MB)
    _Float16* Sh   = (_Float16*)d_ws;
    _Float16* Rh   = Sh + (1u << 20);
    _Float16* w2h  = Rh + (1u << 20);
    _Float16* rtn  = w2h + 16384;
    float*    aggK = (float*)(rtn + (1u << 21));

    hipLaunchKernelGGL(prep, dim3(4672), dim3(256), 0, stream,
                       inp, W1, b1, W2, rt, Sh, Rh, w2h, rtn);
    hipLaunchKernelGGL(edge_mfma, dim3(512), dim3(512), 0, stream,
                       Sh, Rh, w2h, rtn, b2, aggK);
    hipLaunchKernelGGL(node_mlp, dim3(512), dim3(256), 0, stream,
                       aggK, inp, Wo1, bo1, Wo2, bo2, Wo3, bo3, (float*)d_out);
}